// Round 5
// baseline (52.535 us; speedup 1.0000x reference)
//
#include <hip/hip_runtime.h>

// SurveyEmbeddings forward:
//   placeholder = (answer<=1) ? answer*lin_w + lin_b : ans_emb[answer]
//   out = LN(placeholder)*ln_g + ln_b + alpha*year_emb[year[b]] + beta*q_emb[q]
//
// out[B=4096, Q=1024, D=16] fp32 (268 MB) — memory-bound, write-dominated.
//
// R2: 2x unroll blew VGPRs -> occupancy halved -> 2x slower.
// R3: no grid-stride loop -> un-hoisted constant loads -> 10% slower.
// R4: R1 shape + launch_bounds(256,8) + int32 + scalar year: 50.8us (5.6TB/s).
// R5: cut the per-iteration dependent chain:
//   - software pipeline: answer prefetch @ distance 2, ans_emb gather @ 1
//   - LN 4-lane reduce via DPP quad_perm (VALU, ~2cy) instead of shfl_xor
//   - one-pass LN: var = E[x^2] - mu^2 (parallel reductions)

typedef float f32x4 __attribute__((ext_vector_type(4)));

#define LN_EPS 1e-5f

// quad_perm DPP: permute within each 4-lane group. VALU op, no LDS pipe.
// ctrl = a|(b<<2)|(c<<4)|(d<<6): dst lane k of quad <- src lane [a,b,c,d][k]
template <int CTRL>
__device__ __forceinline__ float qperm(float x) {
    return __int_as_float(
        __builtin_amdgcn_mov_dpp(__float_as_int(x), CTRL, 0xF, 0xF, true));
}
#define XOR1(x) qperm<0xB1>(x)   // [1,0,3,2] : lane ^= 1
#define XOR2(x) qperm<0x4E>(x)   // [2,3,0,1] : lane ^= 2

template <bool QPOW2>
__global__ __launch_bounds__(256, 8) void survey_fwd(
    const int* __restrict__ year,
    const int* __restrict__ answer,
    const f32x4* __restrict__ ans_emb,   // [VOCAB][4]
    const f32x4* __restrict__ lin_w,     // [4]
    const f32x4* __restrict__ lin_b,     // [4]
    const f32x4* __restrict__ ln_g,      // [4]
    const f32x4* __restrict__ ln_b,      // [4]
    const f32x4* __restrict__ year_emb,  // [N_YEARS][4]
    const f32x4* __restrict__ q_emb,     // [Q][4]
    const float* __restrict__ alpha,
    const float* __restrict__ beta,
    f32x4* __restrict__ out,             // [B*Q][4]
    int total, int nrows, int Q, int qShift)
{
    const int stride = (int)(gridDim.x * blockDim.x);
    int i = (int)(blockIdx.x * blockDim.x + threadIdx.x);
    if (i >= total) return;

    const float A  = alpha[0];
    const float Bc = beta[0];
    const int sub  = threadIdx.x & 3;    // float4 slot within the D=16 row
    const f32x4 g  = ln_g[sub];
    const f32x4 bb = ln_b[sub];

    // ---- software-pipeline prologue ----
    // a: prefetch distance 2; v (gather): distance 1. Prefetch rows are
    // clamped to a valid index; extra loads are harmless.
    const int nlast = nrows - 1;
    int a0 = answer[i >> 2];
    int r1 = (i + stride) >> 2;  if (r1 > nlast) r1 = nlast;
    int a1 = answer[r1];
    f32x4 v0 = ans_emb[a0 * 4 + sub];

    for (; i < total; i += stride) {
        // ---- issue next-next answer load and next gather (no consumer here)
        int r2 = (i + 2 * stride) >> 2;  if (r2 > nlast) r2 = nlast;
        const int a2 = answer[r2];
        const f32x4 v1 = ans_emb[a1 * 4 + sub];

        // ---- consume current (a0, v0) ----
        f32x4 v = v0;
        if (a0 <= 1) {                       // rare continuous branch (~0.05%)
            const f32x4 w  = lin_w[sub];
            const f32x4 lb = lin_b[sub];
            const float af = (float)a0;
            v.x = af * w.x + lb.x;
            v.y = af * w.y + lb.y;
            v.z = af * w.z + lb.z;
            v.w = af * w.w + lb.w;
        }

        // one-pass LN over D=16: parallel sum / sum-of-squares reductions
        float s  = (v.x + v.y) + (v.z + v.w);
        float s2 = v.x * v.x + v.y * v.y + v.z * v.z + v.w * v.w;
        s  += XOR1(s);   s2 += XOR1(s2);
        s  += XOR2(s);   s2 += XOR2(s2);
        const float mu  = s * 0.0625f;
        const float var = s2 * 0.0625f - mu * mu;
        const float r   = rsqrtf(var + LN_EPS);

        const int row = i >> 2;
        const int b = QPOW2 ? (row >> qShift) : (row / Q);
        const int q = QPOW2 ? (row & (Q - 1)) : (row - b * Q);

        // year index is block-uniform when 64 | Q: scalar load path
        int yr;
        if (QPOW2 && qShift >= 6) {
            yr = year[__builtin_amdgcn_readfirstlane(b)];
        } else {
            yr = year[b];
        }
        const f32x4 ye = year_emb[yr * 4 + sub];
        const f32x4 qe = q_emb[q * 4 + sub];     // L2-hot 64KB table

        // o = (v-mu)*r*g + bb + A*ye + Bc*qe  ==  v*(r*g) + (base - mu*r*g)
        f32x4 o;
        const float rgx = r * g.x, rgy = r * g.y, rgz = r * g.z, rgw = r * g.w;
        o.x = v.x * rgx + (bb.x + A * ye.x + Bc * qe.x - mu * rgx);
        o.y = v.y * rgy + (bb.y + A * ye.y + Bc * qe.y - mu * rgy);
        o.z = v.z * rgz + (bb.z + A * ye.z + Bc * qe.z - mu * rgz);
        o.w = v.w * rgw + (bb.w + A * ye.w + Bc * qe.w - mu * rgw);

        __builtin_nontemporal_store(o, &out[i]);  // stream 268MB, keep L2 for tables

        // ---- shift pipeline ----
        a0 = a1;  a1 = a2;  v0 = v1;
    }
}

extern "C" void kernel_launch(void* const* d_in, const int* in_sizes, int n_in,
                              void* d_out, int out_size, void* d_ws, size_t ws_size,
                              hipStream_t stream) {
    const int*   year     = (const int*)d_in[0];
    const int*   answer   = (const int*)d_in[1];
    const f32x4* ans_emb  = (const f32x4*)d_in[2];
    const f32x4* lin_w    = (const f32x4*)d_in[3];
    const f32x4* lin_b    = (const f32x4*)d_in[4];
    const f32x4* ln_g     = (const f32x4*)d_in[5];
    const f32x4* ln_b     = (const f32x4*)d_in[6];
    const f32x4* year_emb = (const f32x4*)d_in[7];
    const f32x4* q_emb    = (const f32x4*)d_in[8];
    const float* alpha    = (const float*)d_in[9];
    const float* beta     = (const float*)d_in[10];
    float*       out      = (float*)d_out;

    const int B     = in_sizes[0];
    const int nrows = in_sizes[1];       // B*Q
    const int Q     = nrows / B;
    const int total = nrows * 4;         // one float4 per lane-task

    int blocks = (total + 255) / 256;
    if (blocks > 8192) blocks = 8192;    // grid-stride: 8 iters/thread at full size

    const bool pow2 = (Q & (Q - 1)) == 0;
    int qShift = 0;
    while ((1 << qShift) < Q) ++qShift;

    if (pow2) {
        survey_fwd<true><<<blocks, 256, 0, stream>>>(
            year, answer, ans_emb, lin_w, lin_b, ln_g, ln_b, year_emb, q_emb,
            alpha, beta, (f32x4*)out, total, nrows, Q, qShift);
    } else {
        survey_fwd<false><<<blocks, 256, 0, stream>>>(
            year, answer, ans_emb, lin_w, lin_b, ln_g, ln_b, year_emb, q_emb,
            alpha, beta, (f32x4*)out, total, nrows, Q, qShift);
    }
}

// Round 6
// 48.940 us; speedup vs baseline: 1.0734x; 1.0734x over previous
//
#include <hip/hip_runtime.h>

// SurveyEmbeddings forward:
//   placeholder = (answer<=1) ? answer*lin_w + lin_b : ans_emb[answer]
//   out = LN(placeholder)*ln_g + ln_b + alpha*year_emb[year[b]] + beta*q_emb[q]
//
// out[B=4096, Q=1024, D=16] fp32 (268 MB) — memory-bound, write-dominated.
//
// R2: 2x unroll blew VGPRs -> occupancy halved -> 2x slower.
// R3: no grid-stride loop -> un-hoisted constant loads -> 10% slower.
// R4: grid-stride + launch_bounds(256,8) + int32 + scalar year: 50.8us (5.6TB/s). BEST.
// R5: software pipeline + DPP reduce: 52.5us — extra live state, no gain;
//     confirms we are NOT latency-bound (8 waves/SIMD has ~4k cyc slack/iter).
// R6: R4 body unchanged; ONLY change = grid capped at 2048 blocks
//     (= exactly 32 waves/CU in ONE dispatch round, vs 4 rounds at 8192).
//     Hypothesis: round-boundary drain/refill bubbles + tail cost ~3-5us.

typedef float f32x4 __attribute__((ext_vector_type(4)));

#define LN_EPS 1e-5f

template <bool QPOW2>
__global__ __launch_bounds__(256, 8) void survey_fwd(
    const int* __restrict__ year,
    const int* __restrict__ answer,
    const f32x4* __restrict__ ans_emb,   // [VOCAB][4]
    const f32x4* __restrict__ lin_w,     // [4]
    const f32x4* __restrict__ lin_b,     // [4]
    const f32x4* __restrict__ ln_g,      // [4]
    const f32x4* __restrict__ ln_b,      // [4]
    const f32x4* __restrict__ year_emb,  // [N_YEARS][4]
    const f32x4* __restrict__ q_emb,     // [Q][4]
    const float* __restrict__ alpha,
    const float* __restrict__ beta,
    f32x4* __restrict__ out,             // [B*Q][4]
    int total, int Q, int qShift)
{
    const float A  = alpha[0];
    const float Bc = beta[0];

    const int sub = threadIdx.x & 3;     // float4 slot within the D=16 row
    const f32x4 g  = ln_g[sub];
    const f32x4 bb = ln_b[sub];

    const int stride = (int)(gridDim.x * blockDim.x);
    int i = (int)(blockIdx.x * blockDim.x + threadIdx.x);

    for (; i < total; i += stride) {
        const int row = i >> 2;
        const int a   = answer[row];       // 4 lanes broadcast-read same addr

        // categorical branch: gather 16B of the 64B embedding row (L2-hot)
        f32x4 v = ans_emb[a * 4 + sub];

        // continuous branch — rare (~0.05%); table loads stay inside so
        // lin_w/lin_b don't occupy hot-path VGPRs
        if (a <= 1) {
            const f32x4 w  = lin_w[sub];
            const f32x4 lb = lin_b[sub];
            const float af = (float)a;
            v.x = af * w.x + lb.x;
            v.y = af * w.y + lb.y;
            v.z = af * w.z + lb.z;
            v.w = af * w.w + lb.w;
        }

        // LayerNorm over D=16 across the 4-lane group
        float s = v.x + v.y + v.z + v.w;
        s += __shfl_xor(s, 1);
        s += __shfl_xor(s, 2);
        const float mu = s * 0.0625f;

        const float dx = v.x - mu, dy = v.y - mu, dz = v.z - mu, dw = v.w - mu;
        float ss = dx * dx + dy * dy + dz * dz + dw * dw;
        ss += __shfl_xor(ss, 1);
        ss += __shfl_xor(ss, 2);
        const float r = rsqrtf(ss * 0.0625f + LN_EPS);

        const int b = QPOW2 ? (row >> qShift) : (row / Q);
        const int q = QPOW2 ? (row & (Q - 1)) : (row - b * Q);

        // year index is uniform across the block when Q % 64 == 0
        // (a 256-thread block covers 64 consecutive rows, 64 | Q):
        // readfirstlane -> scalar load path, one less VMEM per iteration.
        int yr;
        if (QPOW2 && qShift >= 6) {
            const int b_u = __builtin_amdgcn_readfirstlane(b);
            yr = year[b_u];
        } else {
            yr = year[b];
        }
        const f32x4 ye = year_emb[yr * 4 + sub];
        const f32x4 qe = q_emb[q * 4 + sub];   // L2-hot 64KB table

        f32x4 o;
        o.x = dx * r * g.x + bb.x + A * ye.x + Bc * qe.x;
        o.y = dy * r * g.y + bb.y + A * ye.y + Bc * qe.y;
        o.z = dz * r * g.z + bb.z + A * ye.z + Bc * qe.z;
        o.w = dw * r * g.w + bb.w + A * ye.w + Bc * qe.w;

        __builtin_nontemporal_store(o, &out[i]);  // stream 268MB, keep L2 for tables
    }
}

extern "C" void kernel_launch(void* const* d_in, const int* in_sizes, int n_in,
                              void* d_out, int out_size, void* d_ws, size_t ws_size,
                              hipStream_t stream) {
    const int*   year     = (const int*)d_in[0];
    const int*   answer   = (const int*)d_in[1];
    const f32x4* ans_emb  = (const f32x4*)d_in[2];
    const f32x4* lin_w    = (const f32x4*)d_in[3];
    const f32x4* lin_b    = (const f32x4*)d_in[4];
    const f32x4* ln_g     = (const f32x4*)d_in[5];
    const f32x4* ln_b     = (const f32x4*)d_in[6];
    const f32x4* year_emb = (const f32x4*)d_in[7];
    const f32x4* q_emb    = (const f32x4*)d_in[8];
    const float* alpha    = (const float*)d_in[9];
    const float* beta     = (const float*)d_in[10];
    float*       out      = (float*)d_out;

    const int B     = in_sizes[0];
    const int nrows = in_sizes[1];       // B*Q
    const int Q     = nrows / B;
    const int total = nrows * 4;         // one float4 per lane-task

    int blocks = (total + 255) / 256;
    // 2048 blocks x 256 thr = 8192 waves = exactly 32 waves/CU on 256 CUs:
    // the whole grid is resident in ONE dispatch round (vs 4 rounds at 8192
    // blocks), eliminating round-boundary drain/refill and tail-drain cost.
    if (blocks > 2048) blocks = 2048;    // 32 iters/thread at full size

    const bool pow2 = (Q & (Q - 1)) == 0;
    int qShift = 0;
    while ((1 << qShift) < Q) ++qShift;

    if (pow2) {
        survey_fwd<true><<<blocks, 256, 0, stream>>>(
            year, answer, ans_emb, lin_w, lin_b, ln_g, ln_b, year_emb, q_emb,
            alpha, beta, (f32x4*)out, total, Q, qShift);
    } else {
        survey_fwd<false><<<blocks, 256, 0, stream>>>(
            year, answer, ans_emb, lin_w, lin_b, ln_g, ln_b, year_emb, q_emb,
            alpha, beta, (f32x4*)out, total, Q, qShift);
    }
}